// Round 2
// baseline (324.426 us; speedup 1.0000x reference)
//
#include <hip/hip_runtime.h>
#include <hip/hip_bf16.h>
#include <hip/hip_fp16.h>

#define D 64
#define GRAPHS 128

using bf16x8 = __attribute__((ext_vector_type(8))) short;   // 8 bf16 (4 VGPRs)
using f32x4  = __attribute__((ext_vector_type(4))) float;

// ---------------- small helpers ----------------

__device__ __forceinline__ float bf2f(unsigned short u) {
    return __uint_as_float(((unsigned)u) << 16);
}
__device__ __forceinline__ unsigned short f2bf(float f) {
    unsigned u = __float_as_uint(f);
    unsigned r = (u + 0x7FFFu + ((u >> 16) & 1u)) >> 16;   // RNE
    return (unsigned short)r;
}

// ---------------- pass 1: degree histogram (fire-and-forget) + W/x prep ----------------
// Histogram atomics carry NO return use -> global_atomic_add without sc0, no wait chain.
// x->H segment: 8 elems/thread (2x float4 read, one 16B bf16 store).

__global__ void deg_prep_kernel(const int* __restrict__ dst, int* __restrict__ deg,
                                int E, int EB4,
                                const float* __restrict__ W0, const float* __restrict__ W1,
                                unsigned short* __restrict__ WF0, unsigned short* __restrict__ WF1,
                                const float* __restrict__ x, unsigned short* __restrict__ H, int NH) {
    int b = blockIdx.x;
    if (b < EB4) {
        int e0 = (b * 256 + threadIdx.x) * 4;
        if (e0 + 4 <= E) {
            int4 d4 = *(const int4*)(dst + e0);
            atomicAdd(&deg[d4.x], 1);
            atomicAdd(&deg[d4.y], 1);
            atomicAdd(&deg[d4.z], 1);
            atomicAdd(&deg[d4.w], 1);
        } else {
            for (int e = e0; e < E; ++e) atomicAdd(&deg[dst[e]], 1);
        }
    } else if (b < EB4 + 128) {
        // Wfrag[kt][ct][lane][j]: B[k= kt*32 + (lane>>4)*8 + j][n= ct*16 + (lane&15)]
        int idx = (b - EB4) * 256 + threadIdx.x;   // 32768 = 2 * 16384
        int i = idx & 16383;
        int j = i & 7, lane = (i >> 3) & 63, ct = (i >> 9) & 3, kt = i >> 11;
        int n = ct * 16 + (lane & 15);
        int k = kt * 32 + (lane >> 4) * 8 + j;
        if (idx < 16384) WF0[i] = f2bf(W0[k * 64 + n]);
        else             WF1[i] = f2bf(W1[k * 64 + n]);
    } else {
        int i = (b - EB4 - 128) * 256 + threadIdx.x;   // i over N*8 groups of 8 feats
        if (i < NH) {
            int n = i >> 3, f = (i & 7) * 8;
            float4 x0 = *(const float4*)(x + (size_t)n * 64 + f);
            float4 x1 = *(const float4*)(x + (size_t)n * 64 + f + 4);
            bf16x8 pk;
            pk[0] = f2bf(x0.x); pk[1] = f2bf(x0.y); pk[2] = f2bf(x0.z); pk[3] = f2bf(x0.w);
            pk[4] = f2bf(x1.x); pk[5] = f2bf(x1.y); pk[6] = f2bf(x1.z); pk[7] = f2bf(x1.w);
            *(bf16x8*)(H + (size_t)n * 256 + f) = pk;
        }
    }
}

// ---------------- pass 2: dinv + pdeg + single-pass scan (atomic block ticket) + pad fill ----------------
// Also emits cursor[] = rowstart copy for the scatter-side slot ticketing.

__global__ void scan_all_kernel(const int* __restrict__ deg, float* __restrict__ dinv,
                                int* __restrict__ pdeg, int* __restrict__ rowstart,
                                int* __restrict__ cursor,
                                unsigned int* __restrict__ ep, int* __restrict__ total, int N) {
    __shared__ int s[256];
    __shared__ int base_sh;
    int i = blockIdx.x * 256 + threadIdx.x;
    int d = 0, p = 0;
    if (i < N) {
        d = deg[i];
        dinv[i] = d > 0 ? rsqrtf((float)d) : 0.0f;
        p = (d + 7) & ~7;
        pdeg[i] = p;
    }
    s[threadIdx.x] = p;
    __syncthreads();
    for (int st = 1; st < 256; st <<= 1) {
        int add = (threadIdx.x >= st) ? s[threadIdx.x - st] : 0;
        __syncthreads();
        s[threadIdx.x] += add;
        __syncthreads();
    }
    if (threadIdx.x == 255) base_sh = atomicAdd(total, s[255]);
    __syncthreads();
    if (i < N) {
        int excl = base_sh + s[threadIdx.x] - p;
        rowstart[i] = excl;
        cursor[i] = excl;
        for (int q = excl + d; q < excl + p; ++q) ep[q] = 0u;   // zero-weight pad
    }
}

// ---------------- pass 3: scatter with cursor ticket (4 edges/thread, independent chains) ----------------
// Slot order within a row is arbitrary but the row sum is order-independent -- harmless.

__global__ void scatter_kernel(const int* __restrict__ src, const int* __restrict__ dst,
                               const float* __restrict__ dinv, int* __restrict__ cursor,
                               unsigned int* __restrict__ ep, int E) {
    int e0 = (blockIdx.x * 256 + threadIdx.x) * 4;
    if (e0 + 4 <= E) {
        int4 s4 = *(const int4*)(src + e0);
        int4 d4 = *(const int4*)(dst + e0);
        float v0 = dinv[s4.x], v1 = dinv[s4.y], v2 = dinv[s4.z], v3 = dinv[s4.w];
        int p0 = atomicAdd(&cursor[d4.x], 1);
        int p1 = atomicAdd(&cursor[d4.y], 1);
        int p2 = atomicAdd(&cursor[d4.z], 1);
        int p3 = atomicAdd(&cursor[d4.w], 1);
        ep[p0] = (unsigned)s4.x | ((unsigned)__half_as_ushort(__float2half(v0)) << 16);
        ep[p1] = (unsigned)s4.y | ((unsigned)__half_as_ushort(__float2half(v1)) << 16);
        ep[p2] = (unsigned)s4.z | ((unsigned)__half_as_ushort(__float2half(v2)) << 16);
        ep[p3] = (unsigned)s4.w | ((unsigned)__half_as_ushort(__float2half(v3)) << 16);
    } else {
        for (int e = e0; e < E; ++e) {
            int dd = dst[e], ss = src[e];
            int p = atomicAdd(&cursor[dd], 1);
            ep[p] = (unsigned)ss | ((unsigned)__half_as_ushort(__float2half(dinv[ss])) << 16);
        }
    }
}

// ---------------- pure gather: out_row = dinv[dst] * sum_e dinv[src_e] * in_row[src_e] ----------------
// Wave per dst node. 16 lanes per edge (ushort4 = 4 features/lane); ep entries 4 B.
// Software-pipelined one iteration deep: rows for iter i+1 issue during iter i's FMAs,
// ep words prefetched at depth 2 -> only ONE row-load latency exposure per wave.

#define GROWS 8   // 512 threads/block, 8 nodes/block

__global__ __launch_bounds__(512, 8)
void gather_kernel(const unsigned short* __restrict__ in,   // H + slot_in*64
                   unsigned short* __restrict__ out,        // H + slot_out*64
                   const int* __restrict__ rowstart, const int* __restrict__ pdeg,
                   const float* __restrict__ dinv, const unsigned int* __restrict__ ep, int N) {
    int wid = blockIdx.x * GROWS + (threadIdx.x >> 6);
    if (wid >= N) return;
    int lane = threadIdx.x & 63;
    int g  = lane >> 4;          // edge subgroup 0..3
    int fl = (lane & 15) * 4;    // feature base (4 features per lane)

    int start = __builtin_amdgcn_readfirstlane(rowstart[wid]);
    int cnt   = __builtin_amdgcn_readfirstlane(pdeg[wid]);    // multiple of 8
    float dd  = dinv[wid];                                    // wave-uniform

    float a0 = 0.f, a1 = 0.f, a2 = 0.f, a3 = 0.f;
    float b0 = 0.f, b1 = 0.f, b2 = 0.f, b3 = 0.f;
    unsigned eA = 0, eB = 0;     // ep words for current iteration
    unsigned fA = 0, fB = 0;     // ep words for next iteration
    ushort4 rA = {0, 0, 0, 0}, rB = {0, 0, 0, 0};
    if (cnt > 0) {
        eA = ep[start + g]; eB = ep[start + 4 + g];
        if (cnt > 8) { fA = ep[start + 8 + g]; fB = ep[start + 12 + g]; }
        rA = *(const ushort4*)(in + (size_t)(eA & 0xFFFFu) * 256 + fl);
        rB = *(const ushort4*)(in + (size_t)(eB & 0xFFFFu) * 256 + fl);
    }
    for (int i = 0; i < cnt; i += 8) {
        ushort4 nA = rA, nB = rB;
        unsigned gA = fA, gB = fB;
        if (i + 8 < cnt) {
            nA = *(const ushort4*)(in + (size_t)(fA & 0xFFFFu) * 256 + fl);
            nB = *(const ushort4*)(in + (size_t)(fB & 0xFFFFu) * 256 + fl);
            if (i + 16 < cnt) { fA = ep[start + i + 16 + g]; fB = ep[start + i + 20 + g]; }
        }
        float wA = __half2float(__ushort_as_half((unsigned short)(eA >> 16)));
        float wB = __half2float(__ushort_as_half((unsigned short)(eB >> 16)));
        a0 = fmaf(wA, bf2f(rA.x), a0);
        a1 = fmaf(wA, bf2f(rA.y), a1);
        a2 = fmaf(wA, bf2f(rA.z), a2);
        a3 = fmaf(wA, bf2f(rA.w), a3);
        b0 = fmaf(wB, bf2f(rB.x), b0);
        b1 = fmaf(wB, bf2f(rB.y), b1);
        b2 = fmaf(wB, bf2f(rB.z), b2);
        b3 = fmaf(wB, bf2f(rB.w), b3);
        rA = nA; rB = nB; eA = gA; eB = gB;
    }
    a0 += b0; a1 += b1; a2 += b2; a3 += b3;
    a0 += __shfl_xor(a0, 16, 64); a0 += __shfl_xor(a0, 32, 64);
    a1 += __shfl_xor(a1, 16, 64); a1 += __shfl_xor(a1, 32, 64);
    a2 += __shfl_xor(a2, 16, 64); a2 += __shfl_xor(a2, 32, 64);
    a3 += __shfl_xor(a3, 16, 64); a3 += __shfl_xor(a3, 32, 64);
    if (g == 0) {
        ushort4 pk;
        pk.x = f2bf(a0 * dd); pk.y = f2bf(a1 * dd); pk.z = f2bf(a2 * dd); pk.w = f2bf(a3 * dd);
        *(ushort4*)(out + (size_t)wid * 256 + fl) = pk;
    }
}

// ---------------- layer projection: C[N x 64] = H[N x 256] @ Wflat[256 x 64] ----------------
// MODE 2: H2 = prelu(C+b) (bf16); also block 0 initializes out[] = bout.
// MODE 3: pool fused: LDS bins per block (batch sorted -> ~2 graphs/block), few global atomics.

template<int MODE>
__global__ __launch_bounds__(256, 4)
void tag_gemm_kernel(const unsigned short* __restrict__ H,
                     const unsigned short* __restrict__ Wfrag,
                     const float* __restrict__ bias, const float* __restrict__ alpha,
                     const float* __restrict__ Wout, const int* __restrict__ batch,
                     const float* __restrict__ bout,
                     unsigned short* __restrict__ H2, float* __restrict__ outp, int N) {
    __shared__ float bins[GRAPHS];
    if (MODE == 3) {
        if (threadIdx.x < GRAPHS) bins[threadIdx.x] = 0.0f;
        __syncthreads();
    }
    if (MODE == 2) {
        if (blockIdx.x == 0 && threadIdx.x < GRAPHS) outp[threadIdx.x] = bout[0];
    }

    int w = threadIdx.x >> 6, lane = threadIdx.x & 63;
    int m = lane & 15, quad = lane >> 4;
    int rowbase = blockIdx.x * 64 + w * 16;
    int arow = rowbase + m;
    size_t aoff = (size_t)min(arow, N - 1) * 256 + quad * 8;

    f32x4 acc0 = {0.f, 0.f, 0.f, 0.f}, acc1 = acc0, acc2 = acc0, acc3 = acc0;
#pragma unroll
    for (int kt = 0; kt < 8; ++kt) {
        bf16x8 A = *(const bf16x8*)(H + aoff + kt * 32);
        const unsigned short* wf = Wfrag + ((size_t)(kt * 4) * 64 + lane) * 8;
        bf16x8 B0 = *(const bf16x8*)(wf + 0 * 64 * 8);
        bf16x8 B1 = *(const bf16x8*)(wf + 1 * 64 * 8);
        bf16x8 B2 = *(const bf16x8*)(wf + 2 * 64 * 8);
        bf16x8 B3 = *(const bf16x8*)(wf + 3 * 64 * 8);
        acc0 = __builtin_amdgcn_mfma_f32_16x16x32_bf16(A, B0, acc0, 0, 0, 0);
        acc1 = __builtin_amdgcn_mfma_f32_16x16x32_bf16(A, B1, acc1, 0, 0, 0);
        acc2 = __builtin_amdgcn_mfma_f32_16x16x32_bf16(A, B2, acc2, 0, 0, 0);
        acc3 = __builtin_amdgcn_mfma_f32_16x16x32_bf16(A, B3, acc3, 0, 0, 0);
    }

    float al = alpha[0];
    f32x4 accs[4] = {acc0, acc1, acc2, acc3};
    if (MODE == 2) {
#pragma unroll
        for (int ct = 0; ct < 4; ++ct) {
            int col = ct * 16 + m;
            float b = bias[col];
#pragma unroll
            for (int r = 0; r < 4; ++r) {
                int row = rowbase + quad * 4 + r;
                if (row < N) {
                    float v = accs[ct][r] + b;
                    v = v >= 0.f ? v : al * v;
                    H2[(size_t)row * 256 + col] = f2bf(v);
                }
            }
        }
    } else {
        float rv0 = 0.f, rv1 = 0.f, rv2 = 0.f, rv3 = 0.f;
#pragma unroll
        for (int ct = 0; ct < 4; ++ct) {
            int col = ct * 16 + m;
            float b = bias[col], wo = Wout[col];
            float v;
            v = accs[ct][0] + b; v = v >= 0.f ? v : al * v; rv0 = fmaf(v, wo, rv0);
            v = accs[ct][1] + b; v = v >= 0.f ? v : al * v; rv1 = fmaf(v, wo, rv1);
            v = accs[ct][2] + b; v = v >= 0.f ? v : al * v; rv2 = fmaf(v, wo, rv2);
            v = accs[ct][3] + b; v = v >= 0.f ? v : al * v; rv3 = fmaf(v, wo, rv3);
        }
        float rv[4] = {rv0, rv1, rv2, rv3};
#pragma unroll
        for (int r = 0; r < 4; ++r) {
            float v = rv[r];
            v += __shfl_xor(v, 8, 16);
            v += __shfl_xor(v, 4, 16);
            v += __shfl_xor(v, 2, 16);
            v += __shfl_xor(v, 1, 16);
            int row = rowbase + quad * 4 + r;
            if (m == 0 && row < N) atomicAdd(&bins[batch[row]], v);
        }
        __syncthreads();
        if (threadIdx.x < GRAPHS) {
            float bv = bins[threadIdx.x];
            if (bv != 0.0f) atomicAdd(&outp[threadIdx.x], bv);
        }
    }
}

extern "C" void kernel_launch(void* const* d_in, const int* in_sizes, int n_in,
                              void* d_out, int out_size, void* d_ws, size_t ws_size,
                              hipStream_t stream) {
    const float* x     = (const float*)d_in[0];
    const int*   ei    = (const int*)d_in[1];
    const int*   batch = (const int*)d_in[2];
    const float* W0    = (const float*)d_in[3];
    const float* b0    = (const float*)d_in[4];
    const float* W1    = (const float*)d_in[5];
    const float* b1    = (const float*)d_in[6];
    const float* a0    = (const float*)d_in[7];
    const float* a1    = (const float*)d_in[8];
    const float* Wout  = (const float*)d_in[9];
    const float* bout  = (const float*)d_in[10];

    const int N = in_sizes[0] / D;
    const int E = in_sizes[1] / 2;
    const int* src = ei;
    const int* dst = ei + E;

    size_t off = 0;
    auto alloc = [&](size_t bytes) -> void* {
        void* p = (char*)d_ws + off;
        off = (off + bytes + 255) & ~(size_t)255;
        return p;
    };
    const int NB = (N + 255) / 256;
    int*   deg      = (int*)alloc((size_t)(N + 1) * 4);   // deg[N] = scan ticket counter
    int*   pdeg     = (int*)alloc((size_t)N * 4);
    int*   rowstart = (int*)alloc((size_t)N * 4);
    int*   cursor   = (int*)alloc((size_t)N * 4);
    float* dinv     = (float*)alloc((size_t)N * 4);
    unsigned int* epack = (unsigned int*)alloc(((size_t)E + 8ull * N) * 4);  // padded CSR, 4 B entries
    unsigned short* HA = (unsigned short*)alloc((size_t)N * 256 * 2);        // [N][4][64] bf16
    unsigned short* HB = (unsigned short*)alloc((size_t)N * 256 * 2);
    unsigned short* WF0 = (unsigned short*)alloc(16384 * 2);
    unsigned short* WF1 = (unsigned short*)alloc(16384 * 2);

    const int EB4 = (E + 1023) / 1024;           // 4 edges/thread blocks
    const int NXH = (N * 8 + 255) / 256;         // x->H blocks (8 elems/thread)
    const int NG = (N + GROWS - 1) / GROWS;      // gather blocks (512 thr)
    const int NM = (N + 63) / 64;                // gemm blocks (256 thr)

    // --- CSR build + prep (3 kernels + memset) ---
    hipMemsetAsync(deg, 0, (size_t)(N + 1) * 4, stream);
    deg_prep_kernel<<<EB4 + 128 + NXH, 256, 0, stream>>>(dst, deg, E, EB4,
                                                         W0, W1, WF0, WF1, x, HA, N * 8);
    scan_all_kernel<<<NB, 256, 0, stream>>>(deg, dinv, pdeg, rowstart, cursor, epack, deg + N, N);
    scatter_kernel<<<EB4, 256, 0, stream>>>(src, dst, dinv, cursor, epack, E);

    // --- layer 0: gathers fill HA slots 1..3, fused GEMM+bias+PReLU -> HB slot 0 (+ out init) ---
    gather_kernel<<<NG, 512, 0, stream>>>(HA + 0 * 64, HA + 1 * 64, rowstart, pdeg, dinv, epack, N);
    gather_kernel<<<NG, 512, 0, stream>>>(HA + 1 * 64, HA + 2 * 64, rowstart, pdeg, dinv, epack, N);
    gather_kernel<<<NG, 512, 0, stream>>>(HA + 2 * 64, HA + 3 * 64, rowstart, pdeg, dinv, epack, N);
    tag_gemm_kernel<2><<<NM, 256, 0, stream>>>(HA, WF0, b0, a0, nullptr, nullptr, bout,
                                               HB, (float*)d_out, N);

    // --- layer 1: gathers fill HB slots 1..3, fused GEMM+bias+PReLU+Wout-dot+pool -> out ---
    gather_kernel<<<NG, 512, 0, stream>>>(HB + 0 * 64, HB + 1 * 64, rowstart, pdeg, dinv, epack, N);
    gather_kernel<<<NG, 512, 0, stream>>>(HB + 1 * 64, HB + 2 * 64, rowstart, pdeg, dinv, epack, N);
    gather_kernel<<<NG, 512, 0, stream>>>(HB + 2 * 64, HB + 3 * 64, rowstart, pdeg, dinv, epack, N);
    tag_gemm_kernel<3><<<NM, 256, 0, stream>>>(HB, WF1, b1, a1, Wout, batch, bout,
                                               nullptr, (float*)d_out, N);
}

// Round 3
// 282.775 us; speedup vs baseline: 1.1473x; 1.1473x over previous
//
#include <hip/hip_runtime.h>
#include <hip/hip_bf16.h>
#include <hip/hip_fp16.h>

#define D 64
#define GRAPHS 128

using bf16x8 = __attribute__((ext_vector_type(8))) short;   // 8 bf16 (4 VGPRs)
using f32x4  = __attribute__((ext_vector_type(4))) float;

// ---------------- small helpers ----------------

__device__ __forceinline__ float bf2f(unsigned short u) {
    return __uint_as_float(((unsigned)u) << 16);
}
__device__ __forceinline__ unsigned short f2bf(float f) {
    unsigned u = __float_as_uint(f);
    unsigned r = (u + 0x7FFFu + ((u >> 16) & 1u)) >> 16;   // RNE
    return (unsigned short)r;
}

// ---------------- pass 1: degree histogram + slot ticket (returning atomic), W/x prep ----------------
// Ticket atomic lives HERE because the W-prep and x->H blocks are co-resident and hide its
// latency (round-2 lesson: standalone returning atomics at low occupancy cost 4x).
// 4 edges/thread: int4 dst load, 4 independent atomic chains, coalesced int4 pos store.

__global__ void deg_prep_kernel(const int* __restrict__ dst, int* __restrict__ deg,
                                int* __restrict__ pos, int E, int EB4,
                                const float* __restrict__ W0, const float* __restrict__ W1,
                                unsigned short* __restrict__ WF0, unsigned short* __restrict__ WF1,
                                const float* __restrict__ x, unsigned short* __restrict__ H, int NH) {
    int b = blockIdx.x;
    if (b < EB4) {
        int e0 = (b * 256 + threadIdx.x) * 4;
        if (e0 + 4 <= E) {
            int4 d4 = *(const int4*)(dst + e0);
            int4 p;
            p.x = atomicAdd(&deg[d4.x], 1);
            p.y = atomicAdd(&deg[d4.y], 1);
            p.z = atomicAdd(&deg[d4.z], 1);
            p.w = atomicAdd(&deg[d4.w], 1);
            *(int4*)(pos + e0) = p;
        } else {
            for (int e = e0; e < E; ++e) pos[e] = atomicAdd(&deg[dst[e]], 1);
        }
    } else if (b < EB4 + 128) {
        // Wfrag[kt][ct][lane][j]: B[k= kt*32 + (lane>>4)*8 + j][n= ct*16 + (lane&15)]
        int idx = (b - EB4) * 256 + threadIdx.x;   // 32768 = 2 * 16384
        int i = idx & 16383;
        int j = i & 7, lane = (i >> 3) & 63, ct = (i >> 9) & 3, kt = i >> 11;
        int n = ct * 16 + (lane & 15);
        int k = kt * 32 + (lane >> 4) * 8 + j;
        if (idx < 16384) WF0[i] = f2bf(W0[k * 64 + n]);
        else             WF1[i] = f2bf(W1[k * 64 + n]);
    } else {
        int i = (b - EB4 - 128) * 256 + threadIdx.x;   // i over N*8 groups of 8 feats
        if (i < NH) {
            int n = i >> 3, f = (i & 7) * 8;
            float4 x0 = *(const float4*)(x + (size_t)n * 64 + f);
            float4 x1 = *(const float4*)(x + (size_t)n * 64 + f + 4);
            bf16x8 pk;
            pk[0] = f2bf(x0.x); pk[1] = f2bf(x0.y); pk[2] = f2bf(x0.z); pk[3] = f2bf(x0.w);
            pk[4] = f2bf(x1.x); pk[5] = f2bf(x1.y); pk[6] = f2bf(x1.z); pk[7] = f2bf(x1.w);
            *(bf16x8*)(H + (size_t)n * 256 + f) = pk;
        }
    }
}

// ---------------- pass 2: dinv + pdeg + single-pass scan (atomic block ticket) + pad fill ----------------

__global__ void scan_all_kernel(const int* __restrict__ deg, float* __restrict__ dinv,
                                int* __restrict__ pdeg, int* __restrict__ rowstart,
                                unsigned int* __restrict__ ep, int* __restrict__ total, int N) {
    __shared__ int s[256];
    __shared__ int base_sh;
    int i = blockIdx.x * 256 + threadIdx.x;
    int d = 0, p = 0;
    if (i < N) {
        d = deg[i];
        dinv[i] = d > 0 ? rsqrtf((float)d) : 0.0f;
        p = (d + 7) & ~7;
        pdeg[i] = p;
    }
    s[threadIdx.x] = p;
    __syncthreads();
    for (int st = 1; st < 256; st <<= 1) {
        int add = (threadIdx.x >= st) ? s[threadIdx.x - st] : 0;
        __syncthreads();
        s[threadIdx.x] += add;
        __syncthreads();
    }
    if (threadIdx.x == 255) base_sh = atomicAdd(total, s[255]);
    __syncthreads();
    if (i < N) {
        int excl = base_sh + s[threadIdx.x] - p;
        rowstart[i] = excl;
        for (int q = excl + d; q < excl + p; ++q) ep[q] = 0u;   // zero-weight pad
    }
}

// ---------------- pass 3: atomic-free scatter into padded CSR (4 edges/thread) ----------------

__global__ void scatter_kernel(const int* __restrict__ src, const int* __restrict__ dst,
                               const int* __restrict__ pos, const float* __restrict__ dinv,
                               const int* __restrict__ rowstart, unsigned int* __restrict__ ep, int E) {
    int e0 = (blockIdx.x * 256 + threadIdx.x) * 4;
    if (e0 + 4 <= E) {
        int4 s4 = *(const int4*)(src + e0);
        int4 d4 = *(const int4*)(dst + e0);
        int4 p4 = *(const int4*)(pos + e0);
        float v0 = dinv[s4.x], v1 = dinv[s4.y], v2 = dinv[s4.z], v3 = dinv[s4.w];
        int r0 = rowstart[d4.x], r1 = rowstart[d4.y], r2 = rowstart[d4.z], r3 = rowstart[d4.w];
        ep[r0 + p4.x] = (unsigned)s4.x | ((unsigned)__half_as_ushort(__float2half(v0)) << 16);
        ep[r1 + p4.y] = (unsigned)s4.y | ((unsigned)__half_as_ushort(__float2half(v1)) << 16);
        ep[r2 + p4.z] = (unsigned)s4.z | ((unsigned)__half_as_ushort(__float2half(v2)) << 16);
        ep[r3 + p4.w] = (unsigned)s4.w | ((unsigned)__half_as_ushort(__float2half(v3)) << 16);
    } else {
        for (int e = e0; e < E; ++e) {
            int dd = dst[e], ss = src[e];
            ep[rowstart[dd] + pos[e]] = (unsigned)ss | ((unsigned)__half_as_ushort(__float2half(dinv[ss])) << 16);
        }
    }
}

// ---------------- pure gather: out_row = dinv[dst] * sum_e dinv[src_e] * in_row[src_e] ----------------
// Wave per dst node. 16 lanes per edge (ushort4 = 4 features/lane); ep entries 4 B;
// next iteration's ep words prefetched before current row FMAs (hides ep->row chain).
// (round-0 schedule, measured-good; the depth-2 variant was VGPR-marginal under (512,8).)

#define GROWS 8   // 512 threads/block, 8 nodes/block

__global__ __launch_bounds__(512, 8)
void gather_kernel(const unsigned short* __restrict__ in,   // H + slot_in*64
                   unsigned short* __restrict__ out,        // H + slot_out*64
                   const int* __restrict__ rowstart, const int* __restrict__ pdeg,
                   const float* __restrict__ dinv, const unsigned int* __restrict__ ep, int N) {
    int wid = blockIdx.x * GROWS + (threadIdx.x >> 6);
    if (wid >= N) return;
    int lane = threadIdx.x & 63;
    int g  = lane >> 4;          // edge subgroup 0..3
    int fl = (lane & 15) * 4;    // feature base (4 features per lane)

    int start = __builtin_amdgcn_readfirstlane(rowstart[wid]);
    int cnt   = __builtin_amdgcn_readfirstlane(pdeg[wid]);    // multiple of 8
    float dd  = dinv[wid];                                    // wave-uniform

    float a0 = 0.f, a1 = 0.f, a2 = 0.f, a3 = 0.f;
    float b0 = 0.f, b1 = 0.f, b2 = 0.f, b3 = 0.f;
    unsigned eA = 0, eB = 0;
    if (cnt > 0) { eA = ep[start + g]; eB = ep[start + 4 + g]; }
    for (int i = 0; i < cnt; i += 8) {
        unsigned cA = eA, cB = eB;
        if (i + 8 < cnt) { eA = ep[start + i + 8 + g]; eB = ep[start + i + 12 + g]; }
        ushort4 rA = *(const ushort4*)(in + (size_t)(cA & 0xFFFFu) * 256 + fl);
        ushort4 rB = *(const ushort4*)(in + (size_t)(cB & 0xFFFFu) * 256 + fl);
        float wA = __half2float(__ushort_as_half((unsigned short)(cA >> 16)));
        float wB = __half2float(__ushort_as_half((unsigned short)(cB >> 16)));
        a0 = fmaf(wA, bf2f(rA.x), a0);
        a1 = fmaf(wA, bf2f(rA.y), a1);
        a2 = fmaf(wA, bf2f(rA.z), a2);
        a3 = fmaf(wA, bf2f(rA.w), a3);
        b0 = fmaf(wB, bf2f(rB.x), b0);
        b1 = fmaf(wB, bf2f(rB.y), b1);
        b2 = fmaf(wB, bf2f(rB.z), b2);
        b3 = fmaf(wB, bf2f(rB.w), b3);
    }
    a0 += b0; a1 += b1; a2 += b2; a3 += b3;
    a0 += __shfl_xor(a0, 16, 64); a0 += __shfl_xor(a0, 32, 64);
    a1 += __shfl_xor(a1, 16, 64); a1 += __shfl_xor(a1, 32, 64);
    a2 += __shfl_xor(a2, 16, 64); a2 += __shfl_xor(a2, 32, 64);
    a3 += __shfl_xor(a3, 16, 64); a3 += __shfl_xor(a3, 32, 64);
    if (g == 0) {
        ushort4 pk;
        pk.x = f2bf(a0 * dd); pk.y = f2bf(a1 * dd); pk.z = f2bf(a2 * dd); pk.w = f2bf(a3 * dd);
        *(ushort4*)(out + (size_t)wid * 256 + fl) = pk;
    }
}

// ---------------- layer projection: C[N x 64] = H[N x 256] @ Wflat[256 x 64] ----------------
// MODE 2: H2 = prelu(C+b) (bf16); also block 0 initializes out[] = bout.
// MODE 3: pool fused: LDS bins per block (batch sorted -> ~2 graphs/block), few global atomics.

template<int MODE>
__global__ __launch_bounds__(256, 4)
void tag_gemm_kernel(const unsigned short* __restrict__ H,
                     const unsigned short* __restrict__ Wfrag,
                     const float* __restrict__ bias, const float* __restrict__ alpha,
                     const float* __restrict__ Wout, const int* __restrict__ batch,
                     const float* __restrict__ bout,
                     unsigned short* __restrict__ H2, float* __restrict__ outp, int N) {
    __shared__ float bins[GRAPHS];
    if (MODE == 3) {
        if (threadIdx.x < GRAPHS) bins[threadIdx.x] = 0.0f;
        __syncthreads();
    }
    if (MODE == 2) {
        if (blockIdx.x == 0 && threadIdx.x < GRAPHS) outp[threadIdx.x] = bout[0];
    }

    int w = threadIdx.x >> 6, lane = threadIdx.x & 63;
    int m = lane & 15, quad = lane >> 4;
    int rowbase = blockIdx.x * 64 + w * 16;
    int arow = rowbase + m;
    size_t aoff = (size_t)min(arow, N - 1) * 256 + quad * 8;

    f32x4 acc0 = {0.f, 0.f, 0.f, 0.f}, acc1 = acc0, acc2 = acc0, acc3 = acc0;
#pragma unroll
    for (int kt = 0; kt < 8; ++kt) {
        bf16x8 A = *(const bf16x8*)(H + aoff + kt * 32);
        const unsigned short* wf = Wfrag + ((size_t)(kt * 4) * 64 + lane) * 8;
        bf16x8 B0 = *(const bf16x8*)(wf + 0 * 64 * 8);
        bf16x8 B1 = *(const bf16x8*)(wf + 1 * 64 * 8);
        bf16x8 B2 = *(const bf16x8*)(wf + 2 * 64 * 8);
        bf16x8 B3 = *(const bf16x8*)(wf + 3 * 64 * 8);
        acc0 = __builtin_amdgcn_mfma_f32_16x16x32_bf16(A, B0, acc0, 0, 0, 0);
        acc1 = __builtin_amdgcn_mfma_f32_16x16x32_bf16(A, B1, acc1, 0, 0, 0);
        acc2 = __builtin_amdgcn_mfma_f32_16x16x32_bf16(A, B2, acc2, 0, 0, 0);
        acc3 = __builtin_amdgcn_mfma_f32_16x16x32_bf16(A, B3, acc3, 0, 0, 0);
    }

    float al = alpha[0];
    f32x4 accs[4] = {acc0, acc1, acc2, acc3};
    if (MODE == 2) {
#pragma unroll
        for (int ct = 0; ct < 4; ++ct) {
            int col = ct * 16 + m;
            float b = bias[col];
#pragma unroll
            for (int r = 0; r < 4; ++r) {
                int row = rowbase + quad * 4 + r;
                if (row < N) {
                    float v = accs[ct][r] + b;
                    v = v >= 0.f ? v : al * v;
                    H2[(size_t)row * 256 + col] = f2bf(v);
                }
            }
        }
    } else {
        float rv0 = 0.f, rv1 = 0.f, rv2 = 0.f, rv3 = 0.f;
#pragma unroll
        for (int ct = 0; ct < 4; ++ct) {
            int col = ct * 16 + m;
            float b = bias[col], wo = Wout[col];
            float v;
            v = accs[ct][0] + b; v = v >= 0.f ? v : al * v; rv0 = fmaf(v, wo, rv0);
            v = accs[ct][1] + b; v = v >= 0.f ? v : al * v; rv1 = fmaf(v, wo, rv1);
            v = accs[ct][2] + b; v = v >= 0.f ? v : al * v; rv2 = fmaf(v, wo, rv2);
            v = accs[ct][3] + b; v = v >= 0.f ? v : al * v; rv3 = fmaf(v, wo, rv3);
        }
        float rv[4] = {rv0, rv1, rv2, rv3};
#pragma unroll
        for (int r = 0; r < 4; ++r) {
            float v = rv[r];
            v += __shfl_xor(v, 8, 16);
            v += __shfl_xor(v, 4, 16);
            v += __shfl_xor(v, 2, 16);
            v += __shfl_xor(v, 1, 16);
            int row = rowbase + quad * 4 + r;
            if (m == 0 && row < N) atomicAdd(&bins[batch[row]], v);
        }
        __syncthreads();
        if (threadIdx.x < GRAPHS) {
            float bv = bins[threadIdx.x];
            if (bv != 0.0f) atomicAdd(&outp[threadIdx.x], bv);
        }
    }
}

extern "C" void kernel_launch(void* const* d_in, const int* in_sizes, int n_in,
                              void* d_out, int out_size, void* d_ws, size_t ws_size,
                              hipStream_t stream) {
    const float* x     = (const float*)d_in[0];
    const int*   ei    = (const int*)d_in[1];
    const int*   batch = (const int*)d_in[2];
    const float* W0    = (const float*)d_in[3];
    const float* b0    = (const float*)d_in[4];
    const float* W1    = (const float*)d_in[5];
    const float* b1    = (const float*)d_in[6];
    const float* a0    = (const float*)d_in[7];
    const float* a1    = (const float*)d_in[8];
    const float* Wout  = (const float*)d_in[9];
    const float* bout  = (const float*)d_in[10];

    const int N = in_sizes[0] / D;
    const int E = in_sizes[1] / 2;
    const int* src = ei;
    const int* dst = ei + E;

    size_t off = 0;
    auto alloc = [&](size_t bytes) -> void* {
        void* p = (char*)d_ws + off;
        off = (off + bytes + 255) & ~(size_t)255;
        return p;
    };
    const int NB = (N + 255) / 256;
    int*   deg      = (int*)alloc((size_t)(N + 1) * 4);   // deg[N] = scan ticket counter
    int*   pdeg     = (int*)alloc((size_t)N * 4);
    int*   rowstart = (int*)alloc((size_t)N * 4);
    float* dinv     = (float*)alloc((size_t)N * 4);
    int*   pos      = (int*)alloc((size_t)E * 4);
    unsigned int* epack = (unsigned int*)alloc(((size_t)E + 8ull * N) * 4);  // padded CSR, 4 B entries
    unsigned short* HA = (unsigned short*)alloc((size_t)N * 256 * 2);        // [N][4][64] bf16
    unsigned short* HB = (unsigned short*)alloc((size_t)N * 256 * 2);
    unsigned short* WF0 = (unsigned short*)alloc(16384 * 2);
    unsigned short* WF1 = (unsigned short*)alloc(16384 * 2);

    const int EB4 = (E + 1023) / 1024;           // 4 edges/thread blocks
    const int NXH = (N * 8 + 255) / 256;         // x->H blocks (8 elems/thread)
    const int NG = (N + GROWS - 1) / GROWS;      // gather blocks (512 thr)
    const int NM = (N + 63) / 64;                // gemm blocks (256 thr)

    // --- CSR build + prep (3 kernels + memset) ---
    hipMemsetAsync(deg, 0, (size_t)(N + 1) * 4, stream);
    deg_prep_kernel<<<EB4 + 128 + NXH, 256, 0, stream>>>(dst, deg, pos, E, EB4,
                                                         W0, W1, WF0, WF1, x, HA, N * 8);
    scan_all_kernel<<<NB, 256, 0, stream>>>(deg, dinv, pdeg, rowstart, epack, deg + N, N);
    scatter_kernel<<<EB4, 256, 0, stream>>>(src, dst, pos, dinv, rowstart, epack, E);

    // --- layer 0: gathers fill HA slots 1..3, fused GEMM+bias+PReLU -> HB slot 0 (+ out init) ---
    gather_kernel<<<NG, 512, 0, stream>>>(HA + 0 * 64, HA + 1 * 64, rowstart, pdeg, dinv, epack, N);
    gather_kernel<<<NG, 512, 0, stream>>>(HA + 1 * 64, HA + 2 * 64, rowstart, pdeg, dinv, epack, N);
    gather_kernel<<<NG, 512, 0, stream>>>(HA + 2 * 64, HA + 3 * 64, rowstart, pdeg, dinv, epack, N);
    tag_gemm_kernel<2><<<NM, 256, 0, stream>>>(HA, WF0, b0, a0, nullptr, nullptr, bout,
                                               HB, (float*)d_out, N);

    // --- layer 1: gathers fill HB slots 1..3, fused GEMM+bias+PReLU+Wout-dot+pool -> out ---
    gather_kernel<<<NG, 512, 0, stream>>>(HB + 0 * 64, HB + 1 * 64, rowstart, pdeg, dinv, epack, N);
    gather_kernel<<<NG, 512, 0, stream>>>(HB + 1 * 64, HB + 2 * 64, rowstart, pdeg, dinv, epack, N);
    gather_kernel<<<NG, 512, 0, stream>>>(HB + 2 * 64, HB + 3 * 64, rowstart, pdeg, dinv, epack, N);
    tag_gemm_kernel<3><<<NM, 256, 0, stream>>>(HB, WF1, b1, a1, Wout, batch, bout,
                                               nullptr, (float*)d_out, N);
}

// Round 4
// 279.789 us; speedup vs baseline: 1.1595x; 1.0107x over previous
//
#include <hip/hip_runtime.h>
#include <hip/hip_bf16.h>
#include <hip/hip_fp16.h>

#define D 64
#define GRAPHS 128

using bf16x8 = __attribute__((ext_vector_type(8))) short;   // 8 bf16 (4 VGPRs)
using f32x4  = __attribute__((ext_vector_type(4))) float;

// ---------------- small helpers ----------------

__device__ __forceinline__ float bf2f(unsigned short u) {
    return __uint_as_float(((unsigned)u) << 16);
}
__device__ __forceinline__ unsigned short f2bf(float f) {
    unsigned u = __float_as_uint(f);
    unsigned r = (u + 0x7FFFu + ((u >> 16) & 1u)) >> 16;   // RNE
    return (unsigned short)r;
}

// ---------------- pass 1: degree histogram + slot ticket (returning atomic), W/x prep ----------------
// Ticket atomic lives HERE because the W-prep and x->H blocks are co-resident and hide its
// latency (round-2 lesson: standalone returning atomics at low occupancy cost 4x).
// NOTE (round-3 lesson): the 800K returning device-scope atomics execute at the coherent
// point (memory-side RMW) -- vectorization around them is neutral; ~40 us is structural
// until the CSR build is replaced by a sort/binning scheme.

__global__ void deg_prep_kernel(const int* __restrict__ dst, int* __restrict__ deg,
                                int* __restrict__ pos, int E, int EB4,
                                const float* __restrict__ W0, const float* __restrict__ W1,
                                unsigned short* __restrict__ WF0, unsigned short* __restrict__ WF1,
                                const float* __restrict__ x, unsigned short* __restrict__ H, int NH) {
    int b = blockIdx.x;
    if (b < EB4) {
        int e0 = (b * 256 + threadIdx.x) * 4;
        if (e0 + 4 <= E) {
            int4 d4 = *(const int4*)(dst + e0);
            int4 p;
            p.x = atomicAdd(&deg[d4.x], 1);
            p.y = atomicAdd(&deg[d4.y], 1);
            p.z = atomicAdd(&deg[d4.z], 1);
            p.w = atomicAdd(&deg[d4.w], 1);
            *(int4*)(pos + e0) = p;
        } else {
            for (int e = e0; e < E; ++e) pos[e] = atomicAdd(&deg[dst[e]], 1);
        }
    } else if (b < EB4 + 128) {
        // Wfrag[kt][ct][lane][j]: B[k= kt*32 + (lane>>4)*8 + j][n= ct*16 + (lane&15)]
        int idx = (b - EB4) * 256 + threadIdx.x;   // 32768 = 2 * 16384
        int i = idx & 16383;
        int j = i & 7, lane = (i >> 3) & 63, ct = (i >> 9) & 3, kt = i >> 11;
        int n = ct * 16 + (lane & 15);
        int k = kt * 32 + (lane >> 4) * 8 + j;
        if (idx < 16384) WF0[i] = f2bf(W0[k * 64 + n]);
        else             WF1[i] = f2bf(W1[k * 64 + n]);
    } else {
        int i = (b - EB4 - 128) * 256 + threadIdx.x;   // i over N*8 groups of 8 feats
        if (i < NH) {
            int n = i >> 3, f = (i & 7) * 8;
            float4 x0 = *(const float4*)(x + (size_t)n * 64 + f);
            float4 x1 = *(const float4*)(x + (size_t)n * 64 + f + 4);
            bf16x8 pk;
            pk[0] = f2bf(x0.x); pk[1] = f2bf(x0.y); pk[2] = f2bf(x0.z); pk[3] = f2bf(x0.w);
            pk[4] = f2bf(x1.x); pk[5] = f2bf(x1.y); pk[6] = f2bf(x1.z); pk[7] = f2bf(x1.w);
            *(bf16x8*)(H + (size_t)n * 256 + f) = pk;
        }
    }
}

// ---------------- pass 2: dinv + pdeg + single-pass scan (atomic block ticket) + pad fill ----------------

__global__ void scan_all_kernel(const int* __restrict__ deg, float* __restrict__ dinv,
                                int* __restrict__ pdeg, int* __restrict__ rowstart,
                                unsigned int* __restrict__ ep, int* __restrict__ total, int N) {
    __shared__ int s[256];
    __shared__ int base_sh;
    int i = blockIdx.x * 256 + threadIdx.x;
    int d = 0, p = 0;
    if (i < N) {
        d = deg[i];
        dinv[i] = d > 0 ? rsqrtf((float)d) : 0.0f;
        p = (d + 7) & ~7;
        pdeg[i] = p;
    }
    s[threadIdx.x] = p;
    __syncthreads();
    for (int st = 1; st < 256; st <<= 1) {
        int add = (threadIdx.x >= st) ? s[threadIdx.x - st] : 0;
        __syncthreads();
        s[threadIdx.x] += add;
        __syncthreads();
    }
    if (threadIdx.x == 255) base_sh = atomicAdd(total, s[255]);
    __syncthreads();
    if (i < N) {
        int excl = base_sh + s[threadIdx.x] - p;
        rowstart[i] = excl;
        for (int q = excl + d; q < excl + p; ++q) ep[q] = 0u;   // zero-weight pad
    }
}

// ---------------- pass 3: atomic-free scatter into padded CSR (4 edges/thread) ----------------

__global__ void scatter_kernel(const int* __restrict__ src, const int* __restrict__ dst,
                               const int* __restrict__ pos, const float* __restrict__ dinv,
                               const int* __restrict__ rowstart, unsigned int* __restrict__ ep, int E) {
    int e0 = (blockIdx.x * 256 + threadIdx.x) * 4;
    if (e0 + 4 <= E) {
        int4 s4 = *(const int4*)(src + e0);
        int4 d4 = *(const int4*)(dst + e0);
        int4 p4 = *(const int4*)(pos + e0);
        float v0 = dinv[s4.x], v1 = dinv[s4.y], v2 = dinv[s4.z], v3 = dinv[s4.w];
        int r0 = rowstart[d4.x], r1 = rowstart[d4.y], r2 = rowstart[d4.z], r3 = rowstart[d4.w];
        ep[r0 + p4.x] = (unsigned)s4.x | ((unsigned)__half_as_ushort(__float2half(v0)) << 16);
        ep[r1 + p4.y] = (unsigned)s4.y | ((unsigned)__half_as_ushort(__float2half(v1)) << 16);
        ep[r2 + p4.z] = (unsigned)s4.z | ((unsigned)__half_as_ushort(__float2half(v2)) << 16);
        ep[r3 + p4.w] = (unsigned)s4.w | ((unsigned)__half_as_ushort(__float2half(v3)) << 16);
    } else {
        for (int e = e0; e < E; ++e) {
            int dd = dst[e], ss = src[e];
            ep[rowstart[dd] + pos[e]] = (unsigned)ss | ((unsigned)__half_as_ushort(__float2half(dinv[ss])) << 16);
        }
    }
}

// ---------------- pure gather: out_row = dinv[dst] * sum_e dinv[src_e] * in_row[src_e] ----------------
// WIDE variant (round 4): 8 lanes per edge, bf16x8 (16 B) row load per lane.
// Per iteration the wave covers 16 in-flight edges with the same 2 VMEM slots/lane
// (vs 8 edges with 2x8B before) -> 2x memory concurrency per wave, half the
// latency-exposed iterations. ep for the next iteration prefetched before current FMAs.
// Tail: pdeg is a multiple of 8; an odd half-iteration uses eB=0 (weight-0, reads row 0).

#define GROWS 8   // 512 threads/block, 8 nodes/block

__global__ __launch_bounds__(512, 8)
void gather_kernel(const unsigned short* __restrict__ in,   // H + slot_in*64
                   unsigned short* __restrict__ out,        // H + slot_out*64
                   const int* __restrict__ rowstart, const int* __restrict__ pdeg,
                   const float* __restrict__ dinv, const unsigned int* __restrict__ ep, int N) {
    int wid = blockIdx.x * GROWS + (threadIdx.x >> 6);
    if (wid >= N) return;
    int lane = threadIdx.x & 63;
    int g  = lane >> 3;          // edge subgroup 0..7
    int fl = (lane & 7) * 8;     // feature base (8 features per lane)

    int start = __builtin_amdgcn_readfirstlane(rowstart[wid]);
    int cnt   = __builtin_amdgcn_readfirstlane(pdeg[wid]);    // multiple of 8
    float dd  = dinv[wid];                                    // wave-uniform

    float a0=0.f,a1=0.f,a2=0.f,a3=0.f,a4=0.f,a5=0.f,a6=0.f,a7=0.f;
    float c0=0.f,c1=0.f,c2=0.f,c3=0.f,c4=0.f,c5=0.f,c6=0.f,c7=0.f;
    unsigned eA = 0, eB = 0;
    if (cnt > 0) {
        eA = ep[start + g];
        eB = (8 < cnt) ? ep[start + 8 + g] : 0u;
    }
    for (int i = 0; i < cnt; i += 16) {
        unsigned cA = eA, cB = eB;
        if (i + 16 < cnt) {
            eA = ep[start + i + 16 + g];
            eB = (i + 24 < cnt) ? ep[start + i + 24 + g] : 0u;
        }
        bf16x8 rA = *(const bf16x8*)(in + (size_t)(cA & 0xFFFFu) * 256 + fl);
        bf16x8 rB = *(const bf16x8*)(in + (size_t)(cB & 0xFFFFu) * 256 + fl);
        float wA = __half2float(__ushort_as_half((unsigned short)(cA >> 16)));
        float wB = __half2float(__ushort_as_half((unsigned short)(cB >> 16)));
        a0 = fmaf(wA, bf2f((unsigned short)rA[0]), a0);
        a1 = fmaf(wA, bf2f((unsigned short)rA[1]), a1);
        a2 = fmaf(wA, bf2f((unsigned short)rA[2]), a2);
        a3 = fmaf(wA, bf2f((unsigned short)rA[3]), a3);
        a4 = fmaf(wA, bf2f((unsigned short)rA[4]), a4);
        a5 = fmaf(wA, bf2f((unsigned short)rA[5]), a5);
        a6 = fmaf(wA, bf2f((unsigned short)rA[6]), a6);
        a7 = fmaf(wA, bf2f((unsigned short)rA[7]), a7);
        c0 = fmaf(wB, bf2f((unsigned short)rB[0]), c0);
        c1 = fmaf(wB, bf2f((unsigned short)rB[1]), c1);
        c2 = fmaf(wB, bf2f((unsigned short)rB[2]), c2);
        c3 = fmaf(wB, bf2f((unsigned short)rB[3]), c3);
        c4 = fmaf(wB, bf2f((unsigned short)rB[4]), c4);
        c5 = fmaf(wB, bf2f((unsigned short)rB[5]), c5);
        c6 = fmaf(wB, bf2f((unsigned short)rB[6]), c6);
        c7 = fmaf(wB, bf2f((unsigned short)rB[7]), c7);
    }
    a0 += c0; a1 += c1; a2 += c2; a3 += c3;
    a4 += c4; a5 += c5; a6 += c6; a7 += c7;
    // reduce across the 8 edge subgroups (lane bits 3,4,5)
    a0 += __shfl_xor(a0, 8, 64); a0 += __shfl_xor(a0, 16, 64); a0 += __shfl_xor(a0, 32, 64);
    a1 += __shfl_xor(a1, 8, 64); a1 += __shfl_xor(a1, 16, 64); a1 += __shfl_xor(a1, 32, 64);
    a2 += __shfl_xor(a2, 8, 64); a2 += __shfl_xor(a2, 16, 64); a2 += __shfl_xor(a2, 32, 64);
    a3 += __shfl_xor(a3, 8, 64); a3 += __shfl_xor(a3, 16, 64); a3 += __shfl_xor(a3, 32, 64);
    a4 += __shfl_xor(a4, 8, 64); a4 += __shfl_xor(a4, 16, 64); a4 += __shfl_xor(a4, 32, 64);
    a5 += __shfl_xor(a5, 8, 64); a5 += __shfl_xor(a5, 16, 64); a5 += __shfl_xor(a5, 32, 64);
    a6 += __shfl_xor(a6, 8, 64); a6 += __shfl_xor(a6, 16, 64); a6 += __shfl_xor(a6, 32, 64);
    a7 += __shfl_xor(a7, 8, 64); a7 += __shfl_xor(a7, 16, 64); a7 += __shfl_xor(a7, 32, 64);
    if (g == 0) {
        bf16x8 pk;
        pk[0] = f2bf(a0 * dd); pk[1] = f2bf(a1 * dd);
        pk[2] = f2bf(a2 * dd); pk[3] = f2bf(a3 * dd);
        pk[4] = f2bf(a4 * dd); pk[5] = f2bf(a5 * dd);
        pk[6] = f2bf(a6 * dd); pk[7] = f2bf(a7 * dd);
        *(bf16x8*)(out + (size_t)wid * 256 + fl) = pk;
    }
}

// ---------------- layer projection: C[N x 64] = H[N x 256] @ Wflat[256 x 64] ----------------
// MODE 2: H2 = prelu(C+b) (bf16); also block 0 initializes out[] = bout.
// MODE 3: pool fused: LDS bins per block (batch sorted -> ~2 graphs/block), few global atomics.

template<int MODE>
__global__ __launch_bounds__(256, 4)
void tag_gemm_kernel(const unsigned short* __restrict__ H,
                     const unsigned short* __restrict__ Wfrag,
                     const float* __restrict__ bias, const float* __restrict__ alpha,
                     const float* __restrict__ Wout, const int* __restrict__ batch,
                     const float* __restrict__ bout,
                     unsigned short* __restrict__ H2, float* __restrict__ outp, int N) {
    __shared__ float bins[GRAPHS];
    if (MODE == 3) {
        if (threadIdx.x < GRAPHS) bins[threadIdx.x] = 0.0f;
        __syncthreads();
    }
    if (MODE == 2) {
        if (blockIdx.x == 0 && threadIdx.x < GRAPHS) outp[threadIdx.x] = bout[0];
    }

    int w = threadIdx.x >> 6, lane = threadIdx.x & 63;
    int m = lane & 15, quad = lane >> 4;
    int rowbase = blockIdx.x * 64 + w * 16;
    int arow = rowbase + m;
    size_t aoff = (size_t)min(arow, N - 1) * 256 + quad * 8;

    f32x4 acc0 = {0.f, 0.f, 0.f, 0.f}, acc1 = acc0, acc2 = acc0, acc3 = acc0;
#pragma unroll
    for (int kt = 0; kt < 8; ++kt) {
        bf16x8 A = *(const bf16x8*)(H + aoff + kt * 32);
        const unsigned short* wf = Wfrag + ((size_t)(kt * 4) * 64 + lane) * 8;
        bf16x8 B0 = *(const bf16x8*)(wf + 0 * 64 * 8);
        bf16x8 B1 = *(const bf16x8*)(wf + 1 * 64 * 8);
        bf16x8 B2 = *(const bf16x8*)(wf + 2 * 64 * 8);
        bf16x8 B3 = *(const bf16x8*)(wf + 3 * 64 * 8);
        acc0 = __builtin_amdgcn_mfma_f32_16x16x32_bf16(A, B0, acc0, 0, 0, 0);
        acc1 = __builtin_amdgcn_mfma_f32_16x16x32_bf16(A, B1, acc1, 0, 0, 0);
        acc2 = __builtin_amdgcn_mfma_f32_16x16x32_bf16(A, B2, acc2, 0, 0, 0);
        acc3 = __builtin_amdgcn_mfma_f32_16x16x32_bf16(A, B3, acc3, 0, 0, 0);
    }

    float al = alpha[0];
    f32x4 accs[4] = {acc0, acc1, acc2, acc3};
    if (MODE == 2) {
#pragma unroll
        for (int ct = 0; ct < 4; ++ct) {
            int col = ct * 16 + m;
            float b = bias[col];
#pragma unroll
            for (int r = 0; r < 4; ++r) {
                int row = rowbase + quad * 4 + r;
                if (row < N) {
                    float v = accs[ct][r] + b;
                    v = v >= 0.f ? v : al * v;
                    H2[(size_t)row * 256 + col] = f2bf(v);
                }
            }
        }
    } else {
        float rv0 = 0.f, rv1 = 0.f, rv2 = 0.f, rv3 = 0.f;
#pragma unroll
        for (int ct = 0; ct < 4; ++ct) {
            int col = ct * 16 + m;
            float b = bias[col], wo = Wout[col];
            float v;
            v = accs[ct][0] + b; v = v >= 0.f ? v : al * v; rv0 = fmaf(v, wo, rv0);
            v = accs[ct][1] + b; v = v >= 0.f ? v : al * v; rv1 = fmaf(v, wo, rv1);
            v = accs[ct][2] + b; v = v >= 0.f ? v : al * v; rv2 = fmaf(v, wo, rv2);
            v = accs[ct][3] + b; v = v >= 0.f ? v : al * v; rv3 = fmaf(v, wo, rv3);
        }
        float rv[4] = {rv0, rv1, rv2, rv3};
#pragma unroll
        for (int r = 0; r < 4; ++r) {
            float v = rv[r];
            v += __shfl_xor(v, 8, 16);
            v += __shfl_xor(v, 4, 16);
            v += __shfl_xor(v, 2, 16);
            v += __shfl_xor(v, 1, 16);
            int row = rowbase + quad * 4 + r;
            if (m == 0 && row < N) atomicAdd(&bins[batch[row]], v);
        }
        __syncthreads();
        if (threadIdx.x < GRAPHS) {
            float bv = bins[threadIdx.x];
            if (bv != 0.0f) atomicAdd(&outp[threadIdx.x], bv);
        }
    }
}

extern "C" void kernel_launch(void* const* d_in, const int* in_sizes, int n_in,
                              void* d_out, int out_size, void* d_ws, size_t ws_size,
                              hipStream_t stream) {
    const float* x     = (const float*)d_in[0];
    const int*   ei    = (const int*)d_in[1];
    const int*   batch = (const int*)d_in[2];
    const float* W0    = (const float*)d_in[3];
    const float* b0    = (const float*)d_in[4];
    const float* W1    = (const float*)d_in[5];
    const float* b1    = (const float*)d_in[6];
    const float* a0    = (const float*)d_in[7];
    const float* a1    = (const float*)d_in[8];
    const float* Wout  = (const float*)d_in[9];
    const float* bout  = (const float*)d_in[10];

    const int N = in_sizes[0] / D;
    const int E = in_sizes[1] / 2;
    const int* src = ei;
    const int* dst = ei + E;

    size_t off = 0;
    auto alloc = [&](size_t bytes) -> void* {
        void* p = (char*)d_ws + off;
        off = (off + bytes + 255) & ~(size_t)255;
        return p;
    };
    const int NB = (N + 255) / 256;
    int*   deg      = (int*)alloc((size_t)(N + 1) * 4);   // deg[N] = scan ticket counter
    int*   pdeg     = (int*)alloc((size_t)N * 4);
    int*   rowstart = (int*)alloc((size_t)N * 4);
    float* dinv     = (float*)alloc((size_t)N * 4);
    int*   pos      = (int*)alloc((size_t)E * 4);
    unsigned int* epack = (unsigned int*)alloc(((size_t)E + 8ull * N) * 4);  // padded CSR, 4 B entries
    unsigned short* HA = (unsigned short*)alloc((size_t)N * 256 * 2);        // [N][4][64] bf16
    unsigned short* HB = (unsigned short*)alloc((size_t)N * 256 * 2);
    unsigned short* WF0 = (unsigned short*)alloc(16384 * 2);
    unsigned short* WF1 = (unsigned short*)alloc(16384 * 2);

    const int EB4 = (E + 1023) / 1024;           // 4 edges/thread blocks
    const int NXH = (N * 8 + 255) / 256;         // x->H blocks (8 elems/thread)
    const int NG = (N + GROWS - 1) / GROWS;      // gather blocks (512 thr)
    const int NM = (N + 63) / 64;                // gemm blocks (256 thr)

    // --- CSR build + prep (3 kernels + memset) ---
    hipMemsetAsync(deg, 0, (size_t)(N + 1) * 4, stream);
    deg_prep_kernel<<<EB4 + 128 + NXH, 256, 0, stream>>>(dst, deg, pos, E, EB4,
                                                         W0, W1, WF0, WF1, x, HA, N * 8);
    scan_all_kernel<<<NB, 256, 0, stream>>>(deg, dinv, pdeg, rowstart, epack, deg + N, N);
    scatter_kernel<<<EB4, 256, 0, stream>>>(src, dst, pos, dinv, rowstart, epack, E);

    // --- layer 0: gathers fill HA slots 1..3, fused GEMM+bias+PReLU -> HB slot 0 (+ out init) ---
    gather_kernel<<<NG, 512, 0, stream>>>(HA + 0 * 64, HA + 1 * 64, rowstart, pdeg, dinv, epack, N);
    gather_kernel<<<NG, 512, 0, stream>>>(HA + 1 * 64, HA + 2 * 64, rowstart, pdeg, dinv, epack, N);
    gather_kernel<<<NG, 512, 0, stream>>>(HA + 2 * 64, HA + 3 * 64, rowstart, pdeg, dinv, epack, N);
    tag_gemm_kernel<2><<<NM, 256, 0, stream>>>(HA, WF0, b0, a0, nullptr, nullptr, bout,
                                               HB, (float*)d_out, N);

    // --- layer 1: gathers fill HB slots 1..3, fused GEMM+bias+PReLU+Wout-dot+pool -> out ---
    gather_kernel<<<NG, 512, 0, stream>>>(HB + 0 * 64, HB + 1 * 64, rowstart, pdeg, dinv, epack, N);
    gather_kernel<<<NG, 512, 0, stream>>>(HB + 1 * 64, HB + 2 * 64, rowstart, pdeg, dinv, epack, N);
    gather_kernel<<<NG, 512, 0, stream>>>(HB + 2 * 64, HB + 3 * 64, rowstart, pdeg, dinv, epack, N);
    tag_gemm_kernel<3><<<NM, 256, 0, stream>>>(HB, WF1, b1, a1, Wout, batch, bout,
                                               nullptr, (float*)d_out, N);
}